// Round 6
// baseline (32.659 us; speedup 1.0000x reference)
//
#include <hip/hip_runtime.h>
#include <hip/hip_bf16.h>
#include <math.h>

#define N 64
#define BATCH 2
#define PLANE (N * N)            // 4096
#define VOL (BATCH * N * N * N)  // 524288 elements per slot
#define BIGF 1e8f
#define LP 68                    // padded LDS stride (16B-aligned rows)
#define FBIG 3.4e38f
#define MASK1 0x17u              // labels {0,1,2,4}
#define MASK2 0x13u              // labels {0,1,4}

// ---------------------------------------------------------------------------
// Workspace (bytes):
//   [0, 8*VOL): ushort mids, 4 slots x VOL — slot m = tdm_m, slot 2+m = lz0_m
//              (exact: values <= 7938; 65535 = BIG sentinel)
//   at 8*VOL:             uint64 bits[2][BATCH*N*N]   (boundary y-bitmasks)
//   at 8*VOL + 131072:    float part[256][8]          (per-K2-block partials)
//   at 8*VOL + 131072 + 8192: int cnt                 (K2 completion counter)
// K2 block m = bid>>7:  m=0 -> tsd1 x bnd2 (h_outer); m=1 -> tsd2 x bnd1.
// ---------------------------------------------------------------------------

#define BITS_OFF ((size_t)8 * VOL)
#define PART_OFF (BITS_OFF + (size_t)2 * BATCH * N * N * 8)
#define CNT_OFF (PART_OFF + (size_t)256 * 8 * 4)

typedef __attribute__((ext_vector_type(4))) float f32x4;

// K1: per (mask m, b, x)-plane: column bitmasks -> exact Y-scan (clz/ffs) for
// tdm + level-zero sets -> two Z-envelopes (b128 LDS, 2-op inner) -> mids+bits.
__global__ __launch_bounds__(1024) void edt_yz(const int* __restrict__ mmap,
                                               void* __restrict__ wsv) {
  __shared__ unsigned char colb[3][16][64];    // lz nibbles: plane, y-chunk, z
  __shared__ unsigned long long colm[3][64];   // column masks per plane, z
  __shared__ unsigned long long zmT[64];       // tdm zero-sites per z
  __shared__ unsigned long long zmL[64];       // levelzero zero-sites per z
  __shared__ float Bm1[N][LP];
  __shared__ float Bm2[N][LP];
  const int m = blockIdx.x >> 7;
  const int plane = blockIdx.x & 127;
  const int b = plane >> 6, x = plane & 63;
  const int t = threadIdx.x;
  const int z = t & 63, c = t >> 6;            // chunk c: y in [4c, 4c+4)
  const unsigned lmask = m ? MASK2 : MASK1;
  const size_t bbase = (size_t)(b * N) * PLANE;

  if (blockIdx.x == 0 && t == 0) *(int*)((char*)wsv + CNT_OFF) = 0;

  // ---- load 3 planes' lz bits (x-1, x, x+1) ----
  #pragma unroll
  for (int p = 0; p < 3; ++p) {
    const int xp = x + p - 1;
    unsigned nib = 0;
    if (xp >= 0 && xp < N) {
      const size_t pb = bbase + (size_t)xp * PLANE;
      #pragma unroll
      for (int k = 0; k < 4; ++k) {
        const int y = 4 * c + k;
        nib |= ((lmask >> mmap[pb + y * N + z]) & 1u) << k;
      }
    }
    colb[p][c][z] = (unsigned char)nib;
  }
  __syncthreads();
  if (t < 192) {
    const int p = t >> 6, zz = t & 63;
    unsigned long long v = 0;
    #pragma unroll
    for (int cc = 0; cc < 16; ++cc)
      v |= (unsigned long long)colb[p][cc][zz] << (4 * cc);
    colm[p][zz] = v;
  }
  __syncthreads();
  // ---- derive zero-site masks + boundary bits (one thread per z) ----
  if (t < 64) {
    const unsigned long long cx = colm[1][t];
    unsigned long long nb = colm[0][t] | colm[2][t] | (cx << 1) | (cx >> 1);
    if (t > 0) nb |= colm[1][t - 1];
    if (t < 63) nb |= colm[1][t + 1];
    zmT[t] = ~cx;        // tdm EDT zero-set: lz==0
    zmL[t] = cx | nb;    // levelzero EDT zero-set: lz | dilation
    unsigned long long* bits =
        (unsigned long long*)((char*)wsv + BITS_OFF) + (size_t)m * (BATCH * N * N);
    bits[(size_t)(b * N + x) * N + t] = nb & ~cx;  // boundary: b==1
  }
  __syncthreads();

  // ---- exact Y-scan via clz/ffs on 64-bit column masks (+z^2 folded) ----
  {
    const unsigned long long M0 = zmT[z];
    const unsigned long long M1 = zmL[z];
    const float zs = (float)(z * z);
    #pragma unroll
    for (int k = 0; k < 4; ++k) {
      const int y = 4 * c + k;
      {
        const unsigned long long lo = M0 << (63 - y);
        const int dl = __clzll((long long)lo);
        const int f = __ffsll((long long)(M0 >> y));
        const int d = min(dl, f ? (f - 1) : 99);
        Bm1[y][z] = (d > 63) ? BIGF : (float)(d * d) + zs;
      }
      {
        const unsigned long long lo = M1 << (63 - y);
        const int dl = __clzll((long long)lo);
        const int f = __ffsll((long long)(M1 >> y));
        const int d = min(dl, f ? (f - 1) : 99);
        Bm2[y][z] = (d > 63) ? BIGF : (float)(d * d) + zs;
      }
    }
  }
  __syncthreads();

  // ---- two Z-envelopes, b128 reads: out = zz^2 + min_j (Bm[j] - 2 j zz) ----
  const int y = t & 63, w = t >> 6;  // w in [0,16)
  const f32x4* B1row = (const f32x4*)&Bm1[y][0];
  const f32x4* B2row = (const f32x4*)&Bm2[y][0];
  float a1[4], a2[4], zq[4];
  #pragma unroll
  for (int q = 0; q < 4; ++q) { a1[q] = FBIG; a2[q] = FBIG; zq[q] = (float)(w + 16 * q); }
  float m2j = 0.f;
  #pragma unroll 4
  for (int j4 = 0; j4 < 16; ++j4) {
    const f32x4 f1 = B1row[j4];
    const f32x4 f2 = B2row[j4];
    #pragma unroll
    for (int e = 0; e < 4; ++e) {
      #pragma unroll
      for (int q = 0; q < 4; ++q) {
        a1[q] = fminf(a1[q], fmaf(m2j, zq[q], f1[e]));
        a2[q] = fminf(a2[q], fmaf(m2j, zq[q], f2[e]));
      }
      m2j -= 2.f;
    }
  }
  __syncthreads();  // all reads of Bm done before overwrite
  #pragma unroll
  for (int q = 0; q < 4; ++q) {
    Bm1[y][w + 16 * q] = fmaf(zq[q], zq[q], a1[q]);
    Bm2[y][w + 16 * q] = fmaf(zq[q], zq[q], a2[q]);
  }
  __syncthreads();
  unsigned short* mid1 = (unsigned short*)wsv + (size_t)m * VOL;
  unsigned short* mid2 = (unsigned short*)wsv + (size_t)(2 + m) * VOL;
  const size_t pbase = (size_t)(b * N + x) * PLANE;
  #pragma unroll
  for (int k = 0; k < 4; ++k) {
    const int e = t + 1024 * k;
    mid1[pbase + e] = (unsigned short)fminf(Bm1[e >> 6][e & 63], 65535.f);
    mid2[pbase + e] = (unsigned short)fminf(Bm2[e >> 6][e & 63], 65535.f);
  }
}

// K2: fused double X-envelope (tdm + levelzero of mask m) + hausdorff partials
// + last-block final reduction straight into d_out. LDS tiles transposed so
// the j-stream (x-axis) is contiguous per lane row -> b128 reads.
__global__ __launch_bounds__(1024) void edt_x_fused(void* __restrict__ wsv,
                                                    float* __restrict__ out) {
  __shared__ float A1[N][LP];  // [z][x] (transposed)
  __shared__ float A2[N][LP];
  __shared__ float redS[16], redM[16], redB[16];
  __shared__ int lastFlag;
  const int m = blockIdx.x >> 7;  // 0: tsd1 (pairs bnd2); 1: tsd2 (pairs bnd1)
  const int plane = blockIdx.x & 127;
  const int b = plane >> 6, y = plane & 63;
  const int t = threadIdx.x;
  const int z = t & 63, w = t >> 6;  // w in [0,16)

  const unsigned short* mid1 = (const unsigned short*)wsv + (size_t)m * VOL;
  const unsigned short* mid2 = (const unsigned short*)wsv + (size_t)(2 + m) * VOL;
  #pragma unroll
  for (int k = 0; k < 4; ++k) {
    const int e = t + 1024 * k;
    const int xx = e >> 6, zz = e & 63;
    const float xs = (float)(xx * xx);
    const size_t idx = (size_t)(b * N + xx) * PLANE + y * N + zz;
    const unsigned v1 = mid1[idx];
    const unsigned v2 = mid2[idx];
    A1[zz][xx] = ((v1 == 65535u) ? BIGF : (float)v1) + xs;  // + j^2 folded
    A2[zz][xx] = ((v2 == 65535u) ? BIGF : (float)v2) + xs;
  }
  __syncthreads();

  const f32x4* A1row = (const f32x4*)&A1[z][0];
  const f32x4* A2row = (const f32x4*)&A2[z][0];
  float a1[4], a2[4], xq[4];
  #pragma unroll
  for (int q = 0; q < 4; ++q) { a1[q] = FBIG; a2[q] = FBIG; xq[q] = (float)(w + 16 * q); }
  float m2j = 0.f;
  #pragma unroll 4
  for (int j4 = 0; j4 < 16; ++j4) {
    const f32x4 f1 = A1row[j4];
    const f32x4 f2 = A2row[j4];
    #pragma unroll
    for (int e = 0; e < 4; ++e) {
      #pragma unroll
      for (int q = 0; q < 4; ++q) {
        a1[q] = fminf(a1[q], fmaf(m2j, xq[q], f1[e]));
        a2[q] = fminf(a2[q], fmaf(m2j, xq[q], f2[e]));
      }
      m2j -= 2.f;
    }
  }

  // epilogue: tsd = sqrt(e_tdm) - sqrt(e_lz0); h = bnd_partner * |tsd|
  const unsigned long long* bits =
      (const unsigned long long*)((char*)wsv + BITS_OFF) +
      (size_t)(m == 0 ? 1 : 0) * (BATCH * N * N);
  float hsum = 0.f, hmax = 0.f, bsum = 0.f;
  #pragma unroll
  for (int q = 0; q < 4; ++q) {
    const float e1 = fmaf(xq[q], xq[q], a1[q]);
    const float e2 = fmaf(xq[q], xq[q], a2[q]);
    const float tsd = sqrtf(e1) - sqrtf(e2);
    const int xx = w + 16 * q;
    const unsigned long long bv = bits[(size_t)(b * N + xx) * N + z];
    const float bnd = (float)((bv >> y) & 1ull);
    const float h = bnd * fabsf(tsd);
    hsum += h; bsum += bnd; hmax = fmaxf(hmax, h);
  }
  #pragma unroll
  for (int o = 32; o > 0; o >>= 1) {
    hsum += __shfl_down(hsum, o);
    bsum += __shfl_down(bsum, o);
    hmax = fmaxf(hmax, __shfl_down(hmax, o));
  }
  if (z == 0) { redS[w] = hsum; redB[w] = bsum; redM[w] = hmax; }
  __syncthreads();

  float* part = (float*)((char*)wsv + PART_OFF);
  int* cnt = (int*)((char*)wsv + CNT_OFF);
  if (t == 0) {
    float s = 0.f, bs = 0.f, mx = 0.f;
    #pragma unroll
    for (int i = 0; i < 16; ++i) {
      s += redS[i]; bs += redB[i]; mx = fmaxf(mx, redM[i]);
    }
    float* p = part + (size_t)blockIdx.x * 8;
    p[0] = s; p[1] = bs; p[2] = mx;
    __threadfence();
    const int old = atomicAdd(cnt, 1);
    lastFlag = (old == 255) ? 1 : 0;
  }
  __syncthreads();
  if (lastFlag) {
    __threadfence();  // acquire: other blocks' part[] stores
    float s = 0.f, bs = 0.f, mx = 0.f;
    if (t < 256) {
      const float* p = part + (size_t)t * 8;
      s = p[0]; bs = p[1]; mx = p[2];
    }
    #pragma unroll
    for (int o = 32; o > 0; o >>= 1) {
      s += __shfl_down(s, o);
      bs += __shfl_down(bs, o);
      mx = fmaxf(mx, __shfl_down(mx, o));
    }
    __syncthreads();  // red arrays reuse
    if ((t & 63) == 0 && t < 256) {
      redS[t >> 6] = s; redB[t >> 6] = bs; redM[t >> 6] = mx;
    }
    __syncthreads();
    if (t == 0) {
      // partial idx p<128 -> m=0 (h_outer, bnd2) -> groups 0,1
      const float s_ho = redS[0] + redS[1], b2 = redB[0] + redB[1];
      const float mho = fmaxf(redM[0], redM[1]);
      const float s_hi = redS[2] + redS[3], b1 = redB[2] + redB[3];
      const float mhi = fmaxf(redM[2], redM[3]);
      const float him = s_hi / b1;
      const float hom = s_ho / b2;
      out[0] = him;
      out[1] = mhi;
      out[2] = hom;
      out[3] = mho;
      out[4] = (him - 2.f) * (him - 2.f) + (hom - 2.f) * (hom - 2.f);
    }
  }
}

extern "C" void kernel_launch(void* const* d_in, const int* in_sizes, int n_in,
                              void* d_out, int out_size, void* d_ws,
                              size_t ws_size, hipStream_t stream) {
  (void)in_sizes; (void)n_in; (void)out_size; (void)ws_size;
  const int* mmap = (const int*)d_in[0];
  float* out = (float*)d_out;

  edt_yz<<<2 * BATCH * N, 1024, 0, stream>>>(mmap, d_ws);
  edt_x_fused<<<2 * BATCH * N, 1024, 0, stream>>>(d_ws, out);
}